// Round 1
// baseline (3002.699 us; speedup 1.0000x reference)
//
#include <hip/hip_runtime.h>
#include <hip/hip_bf16.h>

#define EPS 1e-5f

// ---------------------------------------------------------------- cnt init
__global__ __launch_bounds__(256) void k_initcnt(float* cnt, int n) {
    int i = blockIdx.x * 256 + threadIdx.x;
    if (i < n) cnt[i] = 1.0f;   // self-loop contributes 1
}

__global__ __launch_bounds__(256) void k_degree(const int* __restrict__ dst,
                                                float* __restrict__ cnt, int nE) {
    int i = blockIdx.x * 256 + threadIdx.x;
    if (i < nE) atomicAdd(&cnt[dst[i]], 1.0f);
}

// ---------------------------------------------------------------- linear
// out = X @ W + bias, written to BOTH outA and outB.
// outA may alias X (each block reads only its own rows, staged to LDS before
// any write) -> no __restrict__ on X/outA.
__global__ __launch_bounds__(256) void k_linear(const float* X,
                                                const float* __restrict__ W,
                                                const float* __restrict__ bias,
                                                float* outA,
                                                float* __restrict__ outB,
                                                int nRows) {
    __shared__ float xs[64][132];       // 64 rows x 128 k, pad 4 -> 33.8 KB
    int row0 = blockIdx.x * 64;
    int tid = threadIdx.x;
    for (int i = tid; i < 64 * 32; i += 256) {
        int r = i >> 5, c4 = (i & 31) << 2;
        float4 v = make_float4(0.f, 0.f, 0.f, 0.f);
        int row = row0 + r;
        if (row < nRows) v = *(const float4*)(X + (size_t)row * 128 + c4);
        *(float4*)&xs[r][c4] = v;
    }
    __syncthreads();

    int cg = tid & 15, rg = tid >> 4;     // 16 col-groups x 16 row-groups
    int c0 = cg * 8, r0 = rg * 4;         // each thread: 4 rows x 8 cols
    float acc[4][8];
    float4 b0 = *(const float4*)(bias + c0);
    float4 b1 = *(const float4*)(bias + c0 + 4);
#pragma unroll
    for (int r = 0; r < 4; ++r) {
        acc[r][0] = b0.x; acc[r][1] = b0.y; acc[r][2] = b0.z; acc[r][3] = b0.w;
        acc[r][4] = b1.x; acc[r][5] = b1.y; acc[r][6] = b1.z; acc[r][7] = b1.w;
    }

    for (int k0 = 0; k0 < 128; k0 += 4) {
        float4 xv[4];
#pragma unroll
        for (int r = 0; r < 4; ++r) xv[r] = *(const float4*)&xs[r0 + r][k0];
#pragma unroll
        for (int kk = 0; kk < 4; ++kk) {
            int k = k0 + kk;
            float4 w0 = *(const float4*)(W + k * 128 + c0);
            float4 w1 = *(const float4*)(W + k * 128 + c0 + 4);
            float wv[8] = {w0.x, w0.y, w0.z, w0.w, w1.x, w1.y, w1.z, w1.w};
#pragma unroll
            for (int r = 0; r < 4; ++r) {
                float xk = (&xv[r].x)[kk];
#pragma unroll
                for (int j = 0; j < 8; ++j) acc[r][j] = fmaf(xk, wv[j], acc[r][j]);
            }
        }
    }

#pragma unroll
    for (int r = 0; r < 4; ++r) {
        int row = row0 + r0 + r;
        if (row >= nRows) continue;
        float4 o0 = make_float4(acc[r][0], acc[r][1], acc[r][2], acc[r][3]);
        float4 o1 = make_float4(acc[r][4], acc[r][5], acc[r][6], acc[r][7]);
        *(float4*)(outA + (size_t)row * 128 + c0)     = o0;
        *(float4*)(outA + (size_t)row * 128 + c0 + 4) = o1;
        *(float4*)(outB + (size_t)row * 128 + c0)     = o0;
        *(float4*)(outB + (size_t)row * 128 + c0 + 4) = o1;
    }
}

// ---------------------------------------------------------------- scatter
// one wave per edge; lane covers dims {2*lane, 2*lane+1}
__global__ __launch_bounds__(256) void k_scatter(const float* __restrict__ srcf,
                                                 float* __restrict__ dstf,
                                                 const int* __restrict__ srci,
                                                 const int* __restrict__ dsti, int nE) {
    int e = blockIdx.x * 4 + (threadIdx.x >> 6);
    if (e >= nE) return;
    int lane = threadIdx.x & 63;
    int s = srci[e], d = dsti[e];
    const float2 v = *(const float2*)(srcf + (size_t)s * 128 + lane * 2);
    float* dp = dstf + (size_t)d * 128 + lane * 2;
    atomicAdd(dp, v.x);
    atomicAdd(dp + 1, v.y);
}

// ---------------------------------------------------------------- BN+ReLU
// out = relu((msg/cnt - m) * rsqrt(v+eps) * g + be)
__global__ __launch_bounds__(256) void k_bnrelu(const float* __restrict__ msg,
                                                const float* __restrict__ cnt,
                                                const float* __restrict__ g,
                                                const float* __restrict__ be,
                                                const float* __restrict__ m,
                                                const float* __restrict__ v,
                                                float* __restrict__ out, int nRows) {
    int idx = blockIdx.x * 256 + threadIdx.x;
    if (idx >= nRows * 32) return;
    int r = idx >> 5, c4 = (idx & 31) << 2;
    float rc = 1.0f / cnt[r];
    float4 mg = *(const float4*)(msg + (size_t)r * 128 + c4);
    float4 gv = *(const float4*)(g + c4);
    float4 bev = *(const float4*)(be + c4);
    float4 mv = *(const float4*)(m + c4);
    float4 vv = *(const float4*)(v + c4);
    float4 o;
    o.x = fmaxf((mg.x * rc - mv.x) * rsqrtf(vv.x + EPS) * gv.x + bev.x, 0.f);
    o.y = fmaxf((mg.y * rc - mv.y) * rsqrtf(vv.y + EPS) * gv.y + bev.y, 0.f);
    o.z = fmaxf((mg.z * rc - mv.z) * rsqrtf(vv.z + EPS) * gv.z + bev.z, 0.f);
    o.w = fmaxf((mg.w * rc - mv.w) * rsqrtf(vv.w + EPS) * gv.w + bev.w, 0.f);
    *(float4*)(out + (size_t)r * 128 + c4) = o;
}

// ---------------------------------------------------------------- final head
// x = relu(bn2(msg/cnt)); hid = relu(x@Wc1+bc1); out = hid@Wc2+bc2
__global__ __launch_bounds__(256) void k_final(const float* __restrict__ msg,
                                               const float* __restrict__ cnt,
                                               const float* __restrict__ g,
                                               const float* __restrict__ be,
                                               const float* __restrict__ m,
                                               const float* __restrict__ v,
                                               const float* __restrict__ Wc1,
                                               const float* __restrict__ bc1,
                                               const float* __restrict__ Wc2,
                                               const float* __restrict__ bc2,
                                               float* __restrict__ out, int nRows) {
    __shared__ float xs[32][132];    // 16.9 KB
    __shared__ float w1s[128][64];   // 32 KB
    __shared__ float hs[32][68];     // 8.7 KB
    int row0 = blockIdx.x * 32;
    int tid = threadIdx.x;

    for (int i = tid; i < 2048; i += 256) {          // Wc1 [128][64]
        int kk = i >> 4, c4 = (i & 15) << 2;
        *(float4*)&w1s[kk][c4] = *(const float4*)(Wc1 + kk * 64 + c4);
    }
    for (int i = tid; i < 1024; i += 256) {          // x tile with fused bn+relu
        int r = i >> 5, c4 = (i & 31) << 2;
        int row = row0 + r;
        float4 o = make_float4(0.f, 0.f, 0.f, 0.f);
        if (row < nRows) {
            float rc = 1.0f / cnt[row];
            float4 mg = *(const float4*)(msg + (size_t)row * 128 + c4);
            float4 gv = *(const float4*)(g + c4);
            float4 bev = *(const float4*)(be + c4);
            float4 mv = *(const float4*)(m + c4);
            float4 vv = *(const float4*)(v + c4);
            o.x = fmaxf((mg.x * rc - mv.x) * rsqrtf(vv.x + EPS) * gv.x + bev.x, 0.f);
            o.y = fmaxf((mg.y * rc - mv.y) * rsqrtf(vv.y + EPS) * gv.y + bev.y, 0.f);
            o.z = fmaxf((mg.z * rc - mv.z) * rsqrtf(vv.z + EPS) * gv.z + bev.z, 0.f);
            o.w = fmaxf((mg.w * rc - mv.w) * rsqrtf(vv.w + EPS) * gv.w + bev.w, 0.f);
        }
        *(float4*)&xs[r][c4] = o;
    }
    __syncthreads();

    // hidden: 32 rows x 64 cols; thread = 2 rows x 4 cols
    int cg = tid & 15, rg = tid >> 4;
    int c0 = cg * 4, r0 = rg * 2;
    float acc[2][4];
    float4 bc = *(const float4*)(bc1 + c0);
    acc[0][0] = bc.x; acc[0][1] = bc.y; acc[0][2] = bc.z; acc[0][3] = bc.w;
    acc[1][0] = bc.x; acc[1][1] = bc.y; acc[1][2] = bc.z; acc[1][3] = bc.w;
    for (int k = 0; k < 128; ++k) {
        float4 w4 = *(const float4*)&w1s[k][c0];
        float x0 = xs[r0][k], x1 = xs[r0 + 1][k];
        acc[0][0] = fmaf(x0, w4.x, acc[0][0]);
        acc[0][1] = fmaf(x0, w4.y, acc[0][1]);
        acc[0][2] = fmaf(x0, w4.z, acc[0][2]);
        acc[0][3] = fmaf(x0, w4.w, acc[0][3]);
        acc[1][0] = fmaf(x1, w4.x, acc[1][0]);
        acc[1][1] = fmaf(x1, w4.y, acc[1][1]);
        acc[1][2] = fmaf(x1, w4.z, acc[1][2]);
        acc[1][3] = fmaf(x1, w4.w, acc[1][3]);
    }
    float4 h0 = make_float4(fmaxf(acc[0][0], 0.f), fmaxf(acc[0][1], 0.f),
                            fmaxf(acc[0][2], 0.f), fmaxf(acc[0][3], 0.f));
    float4 h1 = make_float4(fmaxf(acc[1][0], 0.f), fmaxf(acc[1][1], 0.f),
                            fmaxf(acc[1][2], 0.f), fmaxf(acc[1][3], 0.f));
    *(float4*)&hs[r0][c0]     = h0;
    *(float4*)&hs[r0 + 1][c0] = h1;
    __syncthreads();

    // out: 32 rows x 2 logits
    if (tid < 64) {
        int r = tid >> 1, oc = tid & 1;
        float s = bc2[oc];
        for (int c = 0; c < 64; ++c) s = fmaf(hs[r][c], Wc2[c * 2 + oc], s);
        int row = row0 + r;
        if (row < nRows) out[(size_t)row * 2 + oc] = s;
    }
}

// ---------------------------------------------------------------- launch
extern "C" void kernel_launch(void* const* d_in, const int* in_sizes, int n_in,
                              void* d_out, int out_size, void* d_ws, size_t ws_size,
                              hipStream_t stream) {
    const float* x   = (const float*)d_in[0];
    const int*   ei  = (const int*)d_in[1];    // [2,E] int32
    const float* W1  = (const float*)d_in[2];
    const float* b1  = (const float*)d_in[3];
    const float* g1  = (const float*)d_in[4];
    const float* be1 = (const float*)d_in[5];
    const float* m1  = (const float*)d_in[6];
    const float* v1  = (const float*)d_in[7];
    const float* W2  = (const float*)d_in[8];
    const float* b2  = (const float*)d_in[9];
    const float* g2  = (const float*)d_in[10];
    const float* be2 = (const float*)d_in[11];
    const float* m2  = (const float*)d_in[12];
    const float* v2  = (const float*)d_in[13];
    const float* Wc1 = (const float*)d_in[14];
    const float* bc1 = (const float*)d_in[15];
    const float* Wc2 = (const float*)d_in[16];
    const float* bc2 = (const float*)d_in[17];

    const int N_ = in_sizes[0] / 128;
    const int E_ = in_sizes[1] / 2;

    float* A   = (float*)d_ws;                 // [N,128] 51.2 MB
    float* B   = A + (size_t)N_ * 128;         // [N,128] 51.2 MB
    float* cnt = B + (size_t)N_ * 128;         // [N]      0.4 MB
    const int* srci = ei;
    const int* dsti = ei + E_;

    k_initcnt<<<(N_ + 255) / 256, 256, 0, stream>>>(cnt, N_);
    k_degree <<<(E_ + 255) / 256, 256, 0, stream>>>(dsti, cnt, E_);

    // layer 1: h1 -> A and B (B doubles as msg buffer pre-seeded with self-loop)
    k_linear <<<(N_ + 63) / 64, 256, 0, stream>>>(x, W1, b1, A, B, N_);
    k_scatter<<<(E_ + 3) / 4, 256, 0, stream>>>(A, B, srci, dsti, E_);
    k_bnrelu <<<((size_t)N_ * 32 + 255) / 256, 256, 0, stream>>>(B, cnt, g1, be1, m1, v1, A, N_);

    // layer 2: h2 -> A (msg seed) and B (gather source)
    k_linear <<<(N_ + 63) / 64, 256, 0, stream>>>(A, W2, b2, A, B, N_);
    k_scatter<<<(E_ + 3) / 4, 256, 0, stream>>>(B, A, srci, dsti, E_);

    // bn2 + relu + MLP head, fused
    k_final  <<<(N_ + 31) / 32, 256, 0, stream>>>(A, cnt, g2, be2, m2, v2,
                                                  Wc1, bc1, Wc2, bc2,
                                                  (float*)d_out, N_);
}

// Round 2
// 723.169 us; speedup vs baseline: 4.1521x; 4.1521x over previous
//
#include <hip/hip_runtime.h>
#include <hip/hip_bf16.h>

#define EPS 1e-5f

// ---------------------------------------------------------------- zero ints
__global__ __launch_bounds__(256) void k_zero(int* p, int n) {
    int i = blockIdx.x * 256 + threadIdx.x;
    if (i < n) p[i] = 0;
}

// ---------------------------------------------------------------- histogram
__global__ __launch_bounds__(256) void k_hist(const int* __restrict__ dst,
                                              int* __restrict__ counts, int nE) {
    int i = blockIdx.x * 256 + threadIdx.x;
    if (i < nE) atomicAdd(&counts[dst[i]], 1);
}

// ---------------------------------------------------------------- scan (3 phases)
// phase 1: per-block (2048 elems) totals
__global__ __launch_bounds__(256) void k_scan1(const int* __restrict__ counts,
                                               int* __restrict__ bsums, int n) {
    __shared__ int sdata[256];
    int base = blockIdx.x * 2048;
    int t = threadIdx.x;
    int s = 0;
#pragma unroll
    for (int i = 0; i < 8; ++i) {
        int idx = base + t * 8 + i;
        if (idx < n) s += counts[idx];
    }
    sdata[t] = s;
    __syncthreads();
    for (int off = 128; off > 0; off >>= 1) {
        if (t < off) sdata[t] += sdata[t + off];
        __syncthreads();
    }
    if (t == 0) bsums[blockIdx.x] = sdata[0];
}

// phase 2: exclusive scan of block sums (nb ~ 49, serial is fine)
__global__ __launch_bounds__(64) void k_scan2(int* __restrict__ bsums, int nb) {
    if (threadIdx.x == 0 && blockIdx.x == 0) {
        int acc = 0;
        for (int i = 0; i < nb; ++i) { int v = bsums[i]; bsums[i] = acc; acc += v; }
    }
}

// phase 3: final exclusive scan -> rowstart[n+1]
__global__ __launch_bounds__(256) void k_scan3(const int* __restrict__ counts,
                                               const int* __restrict__ bsums,
                                               int* __restrict__ rowstart,
                                               int n, int nE) {
    __shared__ int sth[256];
    int base = blockIdx.x * 2048;
    int t = threadIdx.x;
    int loc[8];
    int s = 0;
#pragma unroll
    for (int i = 0; i < 8; ++i) {
        int idx = base + t * 8 + i;
        loc[i] = s;
        s += (idx < n) ? counts[idx] : 0;
    }
    sth[t] = s;
    __syncthreads();
    for (int off = 1; off < 256; off <<= 1) {           // Hillis-Steele inclusive
        int tmp = (t >= off) ? sth[t - off] : 0;
        __syncthreads();
        sth[t] += tmp;
        __syncthreads();
    }
    int excl = sth[t] - s + bsums[blockIdx.x];
#pragma unroll
    for (int i = 0; i < 8; ++i) {
        int idx = base + t * 8 + i;
        if (idx < n) rowstart[idx] = excl + loc[i];
    }
    if (blockIdx.x == 0 && t == 0) rowstart[n] = nE;
}

// ---------------------------------------------------------------- CSR fill
__global__ __launch_bounds__(256) void k_fill(const int* __restrict__ srci,
                                              const int* __restrict__ dsti,
                                              int* __restrict__ cursor,
                                              int* __restrict__ col, int nE) {
    int e = blockIdx.x * 256 + threadIdx.x;
    if (e < nE) {
        int p = atomicAdd(&cursor[dsti[e]], 1);
        col[p] = srci[e];
    }
}

// ---------------------------------------------------------------- linear
// out = X @ W + bias. X staged to LDS per-block before writes, so out may
// NOT alias X here (we always use distinct ping-pong buffers).
__global__ __launch_bounds__(256) void k_linear(const float* __restrict__ X,
                                                const float* __restrict__ W,
                                                const float* __restrict__ bias,
                                                float* __restrict__ out,
                                                int nRows) {
    __shared__ float xs[64][132];       // 64 rows x 128 k, pad 4
    int row0 = blockIdx.x * 64;
    int tid = threadIdx.x;
    for (int i = tid; i < 64 * 32; i += 256) {
        int r = i >> 5, c4 = (i & 31) << 2;
        float4 v = make_float4(0.f, 0.f, 0.f, 0.f);
        int row = row0 + r;
        if (row < nRows) v = *(const float4*)(X + (size_t)row * 128 + c4);
        *(float4*)&xs[r][c4] = v;
    }
    __syncthreads();

    int cg = tid & 15, rg = tid >> 4;     // 16 col-groups x 16 row-groups
    int c0 = cg * 8, r0 = rg * 4;         // each thread: 4 rows x 8 cols
    float acc[4][8];
    float4 b0 = *(const float4*)(bias + c0);
    float4 b1 = *(const float4*)(bias + c0 + 4);
#pragma unroll
    for (int r = 0; r < 4; ++r) {
        acc[r][0] = b0.x; acc[r][1] = b0.y; acc[r][2] = b0.z; acc[r][3] = b0.w;
        acc[r][4] = b1.x; acc[r][5] = b1.y; acc[r][6] = b1.z; acc[r][7] = b1.w;
    }

    for (int k0 = 0; k0 < 128; k0 += 4) {
        float4 xv[4];
#pragma unroll
        for (int r = 0; r < 4; ++r) xv[r] = *(const float4*)&xs[r0 + r][k0];
#pragma unroll
        for (int kk = 0; kk < 4; ++kk) {
            int k = k0 + kk;
            float4 w0 = *(const float4*)(W + k * 128 + c0);
            float4 w1 = *(const float4*)(W + k * 128 + c0 + 4);
            float wv[8] = {w0.x, w0.y, w0.z, w0.w, w1.x, w1.y, w1.z, w1.w};
#pragma unroll
            for (int r = 0; r < 4; ++r) {
                float xk = (&xv[r].x)[kk];
#pragma unroll
                for (int j = 0; j < 8; ++j) acc[r][j] = fmaf(xk, wv[j], acc[r][j]);
            }
        }
    }

#pragma unroll
    for (int r = 0; r < 4; ++r) {
        int row = row0 + r0 + r;
        if (row >= nRows) continue;
        *(float4*)(out + (size_t)row * 128 + c0) =
            make_float4(acc[r][0], acc[r][1], acc[r][2], acc[r][3]);
        *(float4*)(out + (size_t)row * 128 + c0 + 4) =
            make_float4(acc[r][4], acc[r][5], acc[r][6], acc[r][7]);
    }
}

// ---------------------------------------------------------------- gather
// one wave per destination row; lane covers dims {2*lane, 2*lane+1}.
// msg = src[r] (self loop) + sum(src[col[j]]); mean by (deg+1).
// FUSE_BN: out = relu(bn(mean)); else out = mean.
template <bool FUSE_BN>
__global__ __launch_bounds__(256) void k_gather(const float* __restrict__ src,
                                                const int* __restrict__ rowstart,
                                                const int* __restrict__ col,
                                                const float* __restrict__ g,
                                                const float* __restrict__ be,
                                                const float* __restrict__ m,
                                                const float* __restrict__ v,
                                                float* __restrict__ out, int nRows) {
    int r = blockIdx.x * 4 + (threadIdx.x >> 6);
    if (r >= nRows) return;
    int lane = threadIdx.x & 63;
    int d0 = lane * 2;
    int s = rowstart[r], e = rowstart[r + 1];

    float2 acc = *(const float2*)(src + (size_t)r * 128 + d0);   // self loop
    int j = s;
    for (; j + 4 <= e; j += 4) {
        int c0i = col[j], c1i = col[j + 1], c2i = col[j + 2], c3i = col[j + 3];
        float2 a = *(const float2*)(src + (size_t)c0i * 128 + d0);
        float2 b = *(const float2*)(src + (size_t)c1i * 128 + d0);
        float2 c = *(const float2*)(src + (size_t)c2i * 128 + d0);
        float2 d = *(const float2*)(src + (size_t)c3i * 128 + d0);
        acc.x += (a.x + b.x) + (c.x + d.x);
        acc.y += (a.y + b.y) + (c.y + d.y);
    }
    for (; j < e; ++j) {
        int ci = col[j];
        float2 a = *(const float2*)(src + (size_t)ci * 128 + d0);
        acc.x += a.x;
        acc.y += a.y;
    }
    float rc = 1.0f / (float)(e - s + 1);
    float2 o;
    if (FUSE_BN) {
        float2 gv = *(const float2*)(g + d0);
        float2 bev = *(const float2*)(be + d0);
        float2 mv = *(const float2*)(m + d0);
        float2 vv = *(const float2*)(v + d0);
        o.x = fmaxf((acc.x * rc - mv.x) * rsqrtf(vv.x + EPS) * gv.x + bev.x, 0.f);
        o.y = fmaxf((acc.y * rc - mv.y) * rsqrtf(vv.y + EPS) * gv.y + bev.y, 0.f);
    } else {
        o.x = acc.x * rc;
        o.y = acc.y * rc;
    }
    *(float2*)(out + (size_t)r * 128 + d0) = o;
}

// ---------------------------------------------------------------- final head
// x = relu(bn2(mean)) [already computed, FUSE_BN gather]; hid = relu(x@Wc1+bc1);
// out = hid@Wc2+bc2
__global__ __launch_bounds__(256) void k_final(const float* __restrict__ xin,
                                               const float* __restrict__ Wc1,
                                               const float* __restrict__ bc1,
                                               const float* __restrict__ Wc2,
                                               const float* __restrict__ bc2,
                                               float* __restrict__ out, int nRows) {
    __shared__ float xs[32][132];
    __shared__ float w1s[128][64];
    __shared__ float hs[32][68];
    int row0 = blockIdx.x * 32;
    int tid = threadIdx.x;

    for (int i = tid; i < 2048; i += 256) {          // Wc1 [128][64]
        int kk = i >> 4, c4 = (i & 15) << 2;
        *(float4*)&w1s[kk][c4] = *(const float4*)(Wc1 + kk * 64 + c4);
    }
    for (int i = tid; i < 1024; i += 256) {          // x tile
        int r = i >> 5, c4 = (i & 31) << 2;
        int row = row0 + r;
        float4 o = make_float4(0.f, 0.f, 0.f, 0.f);
        if (row < nRows) o = *(const float4*)(xin + (size_t)row * 128 + c4);
        *(float4*)&xs[r][c4] = o;
    }
    __syncthreads();

    // hidden: 32 rows x 64 cols; thread = 2 rows x 4 cols
    int cg = tid & 15, rg = tid >> 4;
    int c0 = cg * 4, r0 = rg * 2;
    float acc[2][4];
    float4 bc = *(const float4*)(bc1 + c0);
    acc[0][0] = bc.x; acc[0][1] = bc.y; acc[0][2] = bc.z; acc[0][3] = bc.w;
    acc[1][0] = bc.x; acc[1][1] = bc.y; acc[1][2] = bc.z; acc[1][3] = bc.w;
    for (int k = 0; k < 128; ++k) {
        float4 w4 = *(const float4*)&w1s[k][c0];
        float x0 = xs[r0][k], x1 = xs[r0 + 1][k];
        acc[0][0] = fmaf(x0, w4.x, acc[0][0]);
        acc[0][1] = fmaf(x0, w4.y, acc[0][1]);
        acc[0][2] = fmaf(x0, w4.z, acc[0][2]);
        acc[0][3] = fmaf(x0, w4.w, acc[0][3]);
        acc[1][0] = fmaf(x1, w4.x, acc[1][0]);
        acc[1][1] = fmaf(x1, w4.y, acc[1][1]);
        acc[1][2] = fmaf(x1, w4.z, acc[1][2]);
        acc[1][3] = fmaf(x1, w4.w, acc[1][3]);
    }
    *(float4*)&hs[r0][c0] = make_float4(fmaxf(acc[0][0], 0.f), fmaxf(acc[0][1], 0.f),
                                        fmaxf(acc[0][2], 0.f), fmaxf(acc[0][3], 0.f));
    *(float4*)&hs[r0 + 1][c0] = make_float4(fmaxf(acc[1][0], 0.f), fmaxf(acc[1][1], 0.f),
                                            fmaxf(acc[1][2], 0.f), fmaxf(acc[1][3], 0.f));
    __syncthreads();

    if (tid < 64) {
        int r = tid >> 1, oc = tid & 1;
        float s = bc2[oc];
        for (int c = 0; c < 64; ++c) s = fmaf(hs[r][c], Wc2[c * 2 + oc], s);
        int row = row0 + r;
        if (row < nRows) out[(size_t)row * 2 + oc] = s;
    }
}

// ---------------------------------------------------------------- launch
extern "C" void kernel_launch(void* const* d_in, const int* in_sizes, int n_in,
                              void* d_out, int out_size, void* d_ws, size_t ws_size,
                              hipStream_t stream) {
    const float* x   = (const float*)d_in[0];
    const int*   ei  = (const int*)d_in[1];    // [2,E] int32
    const float* W1  = (const float*)d_in[2];
    const float* b1  = (const float*)d_in[3];
    const float* g1  = (const float*)d_in[4];
    const float* be1 = (const float*)d_in[5];
    const float* m1  = (const float*)d_in[6];
    const float* v1  = (const float*)d_in[7];
    const float* W2  = (const float*)d_in[8];
    const float* b2  = (const float*)d_in[9];
    const float* g2  = (const float*)d_in[10];
    const float* be2 = (const float*)d_in[11];
    const float* m2  = (const float*)d_in[12];
    const float* v2  = (const float*)d_in[13];
    const float* Wc1 = (const float*)d_in[14];
    const float* bc1 = (const float*)d_in[15];
    const float* Wc2 = (const float*)d_in[16];
    const float* bc2 = (const float*)d_in[17];

    const int N_ = in_sizes[0] / 128;
    const int E_ = in_sizes[1] / 2;
    const int* srci = ei;
    const int* dsti = ei + E_;

    float* A = (float*)d_ws;                       // [N,128]
    float* B = A + (size_t)N_ * 128;               // [N,128]
    int* counts   = (int*)(B + (size_t)N_ * 128);  // N (reused as cursor)
    int* rowstart = counts + N_;                   // N+1
    int* bsums    = rowstart + N_ + 1;             // scan partials
    int* col      = bsums + 256;                   // E

    const int nb = (N_ + 2047) / 2048;

    // ---- CSR build
    k_zero <<<(N_ + 255) / 256, 256, 0, stream>>>(counts, N_);
    k_hist <<<(E_ + 255) / 256, 256, 0, stream>>>(dsti, counts, E_);
    k_scan1<<<nb, 256, 0, stream>>>(counts, bsums, N_);
    k_scan2<<<1, 64, 0, stream>>>(bsums, nb);
    k_scan3<<<nb, 256, 0, stream>>>(counts, bsums, rowstart, N_, E_);
    hipMemcpyAsync(counts, rowstart, (size_t)N_ * sizeof(int),
                   hipMemcpyDeviceToDevice, stream);          // counts := cursor
    k_fill <<<(E_ + 255) / 256, 256, 0, stream>>>(srci, dsti, counts, col, E_);

    // ---- layer 1: h1 = x@W1+b1 -> A ; B = relu(bn1(mean(gather(A))))
    k_linear<<<(N_ + 63) / 64, 256, 0, stream>>>(x, W1, b1, A, N_);
    k_gather<true><<<(N_ + 3) / 4, 256, 0, stream>>>(A, rowstart, col,
                                                     g1, be1, m1, v1, B, N_);

    // ---- layer 2: h2 = B@W2+b2 -> A ; B = relu(bn2(mean(gather(A))))
    k_linear<<<(N_ + 63) / 64, 256, 0, stream>>>(B, W2, b2, A, N_);
    k_gather<true><<<(N_ + 3) / 4, 256, 0, stream>>>(A, rowstart, col,
                                                     g2, be2, m2, v2, B, N_);

    // ---- MLP head
    k_final<<<(N_ + 31) / 32, 256, 0, stream>>>(B, Wc1, bc1, Wc2, bc2,
                                                (float*)d_out, N_);
}